// Round 3
// baseline (432.670 us; speedup 1.0000x reference)
//
#include <hip/hip_runtime.h>

typedef __bf16 bf16;
typedef __attribute__((ext_vector_type(8))) __bf16 bf16x8;
typedef __attribute__((ext_vector_type(4))) float f32x4;
typedef __attribute__((ext_vector_type(4))) unsigned int u32x4;

#define MFMA16(a, b, c) __builtin_amdgcn_mfma_f32_16x16x32_bf16(a, b, c, 0, 0, 0)

#define C_DIM 1024
#define N_TOK 4096
#define BATCH 4
#define HEADS 16
#define HD 64
#define BS 64
#define NB 64
#define M_TOT (BATCH * N_TOK)              // 16384
#define QKV_ELEMS ((size_t)M_TOT * C_DIM)  // 16777216
#define W_ELEMS (C_DIM * C_DIM)            // 1048576
#define VT_LD 200                          // V^T row stride in elems (400B rows)
#define NKT 16                             // K tiles of 64 (C_DIM/64)

// ---------------------------------------------------------------------------
// Dtype detector: flag=0 -> inputs bf16, flag=1 -> inputs f32.
// ---------------------------------------------------------------------------
__global__ void detect_kernel(const unsigned int* __restrict__ x, int* flag) {
    if (threadIdx.x == 0) {
        int cnt = 0;
        for (int i = 0; i < 256; ++i) {
            unsigned int e = (x[i] >> 7) & 0xFFu;
            cnt += (e >= 100u && e <= 140u) ? 1 : 0;
        }
        *flag = (cnt >= 192) ? 0 : 1;
    }
}

__global__ void sentinel_kernel(float* out, float val, int n) {
    int i = blockIdx.x * 256 + threadIdx.x;
    if (i < n) out[i] = val;
}

__device__ __forceinline__ bf16x8 cvt8(f32x4 a, f32x4 b) {
    bf16x8 r;
    r[0] = (bf16)a[0]; r[1] = (bf16)a[1]; r[2] = (bf16)a[2]; r[3] = (bf16)a[3];
    r[4] = (bf16)b[0]; r[5] = (bf16)b[1]; r[6] = (bf16)b[2]; r[7] = (bf16)b[3];
    return r;
}

__device__ __forceinline__ float rd1(const void* p, int i, int isf) {
    return isf ? ((const float*)p)[i] : (float)((const bf16*)p)[i];
}

// ---------------------------------------------------------------------------
// Prepass: convert x + 4 weights to bf16.
// ---------------------------------------------------------------------------
__global__ __launch_bounds__(256) void cvt_kernel(
    const void* __restrict__ x,  bf16* __restrict__ xb,
    const void* __restrict__ w0, const void* __restrict__ w1,
    const void* __restrict__ w2, const void* __restrict__ w3,
    bf16* __restrict__ wb, const int* __restrict__ flag)
{
    const int isf = *flag;
    const int bid = blockIdx.x;
    const void* src;
    bf16* dst;
    size_t off;
    if (bid < 8192) {
        src = x; dst = xb; off = (size_t)bid * 2048;
    } else {
        const int seg = (bid - 8192) >> 9;
        src = seg == 0 ? w0 : (seg == 1 ? w1 : (seg == 2 ? w2 : w3));
        dst = wb + (size_t)seg * W_ELEMS;
        off = (size_t)((bid - 8192) & 511) * 2048;
    }
    const size_t e = off + (size_t)threadIdx.x * 8;
    if (isf) {
        const float* gp = (const float*)src + e;
        *(bf16x8*)(dst + e) = cvt8(*(const f32x4*)gp, *(const f32x4*)(gp + 4));
    } else {
        *(u32x4*)(dst + e) = *(const u32x4*)((const bf16*)src + e);
    }
}

// async 16B global->LDS: lane i lands at (wave-uniform l) + i*16
__device__ __forceinline__ void gload_lds16(const bf16* g, bf16* l) {
    __builtin_amdgcn_global_load_lds(
        (const __attribute__((address_space(1))) void*)g,
        (__attribute__((address_space(3))) void*)l, 16, 0, 0);
}

// ---------------------------------------------------------------------------
// 256x256 8-phase GEMM machinery.
// LDS tiles [256 rows][64 cols] bf16, rows of 128B. Content swizzled:
// 16B-group g of row r holds global col-group (g ^ (r&7)). Staging keeps the
// LDS dest linear (global_load_lds constraint) and pre-swizzles the per-lane
// GLOBAL column; reads apply the same XOR -> conflict-free ds_read_b128.
// A-half h covers rows {h*64..+64} u {128+h*64..+64} (phase-aligned).
// B-half y covers rows {s*64 + y*32 ..+32} for s=0..3.
// ---------------------------------------------------------------------------
__device__ __forceinline__ void stageA(const bf16* __restrict__ src, bf16* lds,
                                       int h, int w, int lane, int m0, int k0) {
#pragma unroll
    for (int l = 0; l < 2; ++l) {
        const int c = w * 2 + l;                       // chunk 0..15, wave-uniform
        const int rowbase = (c >> 3) * 128 + h * 64 + (c & 7) * 8;
        const int grow = m0 + rowbase + (lane >> 3);
        const int gcol = k0 + (((lane & 7) ^ ((lane >> 3) & 7)) << 3);
        gload_lds16(src + (size_t)grow * C_DIM + gcol, lds + rowbase * 64);
    }
}
__device__ __forceinline__ void stageB(const bf16* __restrict__ src, bf16* lds,
                                       int y, int w, int lane, int n0, int k0) {
#pragma unroll
    for (int l = 0; l < 2; ++l) {
        const int c = w * 2 + l;
        const int rowbase = (c >> 2) * 64 + y * 32 + (c & 3) * 8;
        const int grow = n0 + rowbase + (lane >> 3);
        const int gcol = k0 + (((lane & 7) ^ ((lane >> 3) & 7)) << 3);
        gload_lds16(src + (size_t)grow * C_DIM + gcol, lds + rowbase * 64);
    }
}

__device__ __forceinline__ bf16x8 ldsrd(const bf16* base, int row, int kk, int quad) {
    return *(const bf16x8*)((const char*)base +
        row * 128 + ((kk * 64 + quad * 16) ^ ((row & 7) << 4)));
}

// K-loop core: runs the 8-phase (2 K-tiles worth per 2 windows) schedule.
// Race-freedom: tile t+1 is staged during window t into the buffer last read
// in window t-1 (ended, barrier-separated). Each guaranteeing vmcnt sits
// between the MFMA cluster and the phase-ending barrier, so every wave has
// executed it before any wave's next-phase ds_reads. Counted vmcnt(4)
// (= allow 2 half-tiles in flight) in steady state; last window drains 2->0.
#define GEMM256_KLOOP(ASRC, BSRC)                                               \
    {                                                                           \
        bf16* Ab0 = sm;                                                         \
        bf16* Bb0 = sm + 32768;                                                 \
        stageA(ASRC, Ab0, 0, w, lane, m0, 0);                                   \
        stageA(ASRC, Ab0, 1, w, lane, m0, 0);                                   \
        stageB(BSRC, Bb0, 0, w, lane, n0, 0);                                   \
        stageB(BSRC, Bb0, 1, w, lane, n0, 0);                                   \
    }                                                                           \
    asm volatile("s_waitcnt vmcnt(0)" ::: "memory");                            \
    __syncthreads();                                                            \
    for (int t = 0; t < NKT; ++t) {                                             \
        const bool stg = (t + 1) < NKT;                                         \
        bf16* Ab = sm + (t & 1) * 16384;                                        \
        bf16* Bb = sm + 32768 + (t & 1) * 16384;                                \
        bf16* An = sm + ((t + 1) & 1) * 16384;                                  \
        bf16* Bn = sm + 32768 + ((t + 1) & 1) * 16384;                          \
        const int kn = (t + 1) * 64;                                            \
        bf16x8 af[4][2], b0[2][2], b1[2][2];                                    \
        /* phase 0: quad (mh=0, nh=0) */                                        \
        _Pragma("unroll") for (int mi = 0; mi < 4; ++mi)                        \
            _Pragma("unroll") for (int kk = 0; kk < 2; ++kk)                    \
                af[mi][kk] = ldsrd(Ab, wr * 128 + mi * 16 + lr, kk, quad);      \
        _Pragma("unroll") for (int ni = 0; ni < 2; ++ni)                        \
            _Pragma("unroll") for (int kk = 0; kk < 2; ++kk)                    \
                b0[ni][kk] = ldsrd(Bb, wc * 64 + ni * 16 + lr, kk, quad);       \
        if (stg) stageA(ASRC, An, 0, w, lane, m0, kn);                          \
        __builtin_amdgcn_s_barrier();                                           \
        __builtin_amdgcn_s_setprio(1);                                          \
        _Pragma("unroll") for (int kk = 0; kk < 2; ++kk)                        \
            _Pragma("unroll") for (int mi = 0; mi < 4; ++mi)                    \
                _Pragma("unroll") for (int ni = 0; ni < 2; ++ni)                \
                    acc[mi][ni] = MFMA16(af[mi][kk], b0[ni][kk], acc[mi][ni]);  \
        __builtin_amdgcn_s_setprio(0);                                          \
        if (stg) asm volatile("s_waitcnt vmcnt(4)" ::: "memory");               \
        else     asm volatile("s_waitcnt vmcnt(2)" ::: "memory");               \
        __builtin_amdgcn_s_barrier();                                           \
        /* phase 1: quad (mh=0, nh=1) */                                        \
        _Pragma("unroll") for (int ni = 0; ni < 2; ++ni)                        \
            _Pragma("unroll") for (int kk = 0; kk < 2; ++kk)                    \
                b1[ni][kk] = ldsrd(Bb, wc * 64 + 32 + ni * 16 + lr, kk, quad);  \
        if (stg) stageB(BSRC, Bn, 0, w, lane, n0, kn);                          \
        __builtin_amdgcn_s_barrier();                                           \
        __builtin_amdgcn_s_setprio(1);                                          \
        _Pragma("unroll") for (int kk = 0; kk < 2; ++kk)                        \
            _Pragma("unroll") for (int mi = 0; mi < 4; ++mi)                    \
                _Pragma("unroll") for (int ni = 0; ni < 2; ++ni)                \
                    acc[mi][2 + ni] = MFMA16(af[mi][kk], b1[ni][kk], acc[mi][2 + ni]); \
        __builtin_amdgcn_s_setprio(0);                                          \
        if (stg) asm volatile("s_waitcnt vmcnt(4)" ::: "memory");               \
        else     asm volatile("s_waitcnt vmcnt(0)" ::: "memory");               \
        __builtin_amdgcn_s_barrier();                                           \
        /* phase 2: quad (mh=1, nh=0) */                                        \
        _Pragma("unroll") for (int mi = 0; mi < 4; ++mi)                        \
            _Pragma("unroll") for (int kk = 0; kk < 2; ++kk)                    \
                af[mi][kk] = ldsrd(Ab, wr * 128 + 64 + mi * 16 + lr, kk, quad); \
        if (stg) stageB(BSRC, Bn, 1, w, lane, n0, kn);                          \
        __builtin_amdgcn_s_barrier();                                           \
        __builtin_amdgcn_s_setprio(1);                                          \
        _Pragma("unroll") for (int kk = 0; kk < 2; ++kk)                        \
            _Pragma("unroll") for (int mi = 0; mi < 4; ++mi)                    \
                _Pragma("unroll") for (int ni = 0; ni < 2; ++ni)                \
                    acc[4 + mi][ni] = MFMA16(af[mi][kk], b0[ni][kk], acc[4 + mi][ni]); \
        __builtin_amdgcn_s_setprio(0);                                          \
        __builtin_amdgcn_s_barrier();                                           \
        /* phase 3: quad (mh=1, nh=1) */                                        \
        if (stg) stageA(ASRC, An, 1, w, lane, m0, kn);                          \
        __builtin_amdgcn_s_barrier();                                           \
        __builtin_amdgcn_s_setprio(1);                                          \
        _Pragma("unroll") for (int kk = 0; kk < 2; ++kk)                        \
            _Pragma("unroll") for (int mi = 0; mi < 4; ++mi)                    \
                _Pragma("unroll") for (int ni = 0; ni < 2; ++ni)                \
                    acc[4 + mi][2 + ni] = MFMA16(af[mi][kk], b1[ni][kk], acc[4 + mi][2 + ni]); \
        __builtin_amdgcn_s_setprio(0);                                          \
        if (stg) asm volatile("s_waitcnt vmcnt(4)" ::: "memory");               \
        __builtin_amdgcn_s_barrier();                                           \
    }

// ---------------------------------------------------------------------------
// Kernel 1: fused QKV projection, 256x256 8-phase. Grid (12, 64):
// x = which*4 + nblock (12 consecutive wgs share one A-panel), y = m-block.
// ---------------------------------------------------------------------------
__global__ __launch_bounds__(512) void qkv256_kernel(
    const bf16* __restrict__ xb, const bf16* __restrict__ wb,
    const void* __restrict__ bq, const void* __restrict__ bk,
    const void* __restrict__ bv,
    bf16* __restrict__ qo, bf16* __restrict__ ko, bf16* __restrict__ vo,
    const int* __restrict__ flag)
{
    __shared__ __align__(16) bf16 sm[65536];   // 128 KiB: 2 dbuf x (A 32K + B 32K)

    const int isf = *flag;
    const int which = blockIdx.x >> 2;
    const int n0 = (blockIdx.x & 3) * 256;
    const int m0 = blockIdx.y * 256;
    const bf16* W  = wb + (size_t)which * W_ELEMS;
    const void* bia = which == 0 ? bq : (which == 1 ? bk : bv);
    bf16* dst       = which == 0 ? qo : (which == 1 ? ko : vo);

    const int tid = threadIdx.x;
    const int w = tid >> 6, lane = tid & 63;
    const int wr = w >> 2, wc = w & 3;               // 2M x 4N waves
    const int lr = lane & 15, quad = lane >> 4;

    f32x4 acc[8][4] = {};

    GEMM256_KLOOP(xb, W)

    // epilogue: bias + bf16 pack via swizzled LDS bounce, vectorized stores
    __syncthreads();
    float bb[4];
#pragma unroll
    for (int ni = 0; ni < 4; ++ni)
        bb[ni] = rd1(bia, n0 + wc * 64 + ni * 16 + lr, isf);
#pragma unroll
    for (int mi = 0; mi < 8; ++mi)
#pragma unroll
        for (int ni = 0; ni < 4; ++ni)
#pragma unroll
            for (int rr = 0; rr < 4; ++rr) {
                const int row = wr * 128 + mi * 16 + quad * 4 + rr;
                const int col = wc * 64 + ni * 16 + lr;
                *(bf16*)((char*)sm + row * 512 + ((col * 2) ^ ((row & 7) << 4))) =
                    (bf16)(acc[mi][ni][rr] + bb[ni]);
            }
    __syncthreads();
    {
        const int row = tid >> 1, g0 = (tid & 1) * 256;
        const int key = (row & 7) << 4;
#pragma unroll
        for (int j = 0; j < 16; ++j) {
            u32x4 vls = *(const u32x4*)((const char*)sm + row * 512 + ((g0 + j * 16) ^ key));
            *(u32x4*)(dst + (size_t)(m0 + row) * C_DIM + n0 + (g0 >> 1) + j * 8) = vls;
        }
    }
}

// ---------------------------------------------------------------------------
// Kernel 2: block-sparse attention via MFMA (verified round-2 version).
// ---------------------------------------------------------------------------
__global__ __launch_bounds__(256) void attn_kernel(
    const bf16* qb, const bf16* __restrict__ kb,
    const bf16* __restrict__ vb, bf16* ob)
{
    __shared__ __align__(16) bf16 sh[12288 + 64 * VT_LD];
    bf16* Ks = sh;               // 192x64, rows of 128B, col bytes ^ (row&7)<<4
    bf16* Ps = sh;               // 64x192, overlays Ks after phase 1
    bf16* Vt = sh + 12288;       // 64 x VT_LD, col bytes ^ ((dd>>3)&7)<<4

    const int nblk = blockIdx.x, bh = blockIdx.y, tid = threadIdx.x;
    const int b = bh >> 4, h = bh & 15;
    const int w = tid >> 6, lane = tid & 63;
    const int lr = lane & 15, quad = lane >> 4;
    const int grow = b * N_TOK + nblk * BS;
    const int colbase = h * HD;

    bf16x8 aq[2];
#pragma unroll
    for (int ks = 0; ks < 2; ++ks)
        aq[ks] = *(const bf16x8*)(qb + (size_t)(grow + w * 16 + lr) * C_DIM
                                  + colbase + ks * 32 + quad * 8);

    for (int wbk = 0; wbk < 3; ++wbk) {
        const int gb = nblk - 1 + wbk;
        const bool ok = (gb >= 0 && gb < NB);
#pragma unroll
        for (int p = 0; p < 2; ++p) {
            const int e = (p * 256 + tid) * 8;
            const int row = e >> 6, col = e & 63;
            const int boff = (wbk * 64 + row) * 128 + ((col * 2) ^ ((row & 7) << 4));
            u32x4 val = {};
            if (ok)
                val = *(const u32x4*)(kb + (size_t)(b * N_TOK + gb * BS + row) * C_DIM + colbase + col);
            *(u32x4*)((char*)Ks + boff) = val;
        }
    }
#pragma unroll
    for (int t = 0; t < 6; ++t) {
        const int e8 = (t * 256 + tid) * 8;
        const int kk = e8 >> 6, dd0 = e8 & 63;
        const int gb = nblk - 1 + (kk >> 6);
        bf16x8 vv = {};
        if (gb >= 0 && gb < NB)
            vv = *(const bf16x8*)(vb + (size_t)(b * N_TOK + gb * BS + (kk & 63)) * C_DIM + colbase + dd0);
        const int key = ((dd0 >> 3) & 7) << 4;
#pragma unroll
        for (int i = 0; i < 8; ++i) {
            const int boff = (dd0 + i) * (2 * VT_LD) + ((kk * 2) ^ key);
            *(bf16*)((char*)Vt + boff) = vv[i];
        }
    }
    __syncthreads();

    f32x4 s[12];
    __builtin_amdgcn_s_setprio(1);
#pragma unroll
    for (int jt = 0; jt < 12; ++jt) {
        f32x4 a = {};
#pragma unroll
        for (int ks = 0; ks < 2; ++ks) {
            const int boff = (jt * 16 + lr) * 128 + ((ks * 64 + quad * 16) ^ ((lr & 7) << 4));
            bf16x8 bk_ = *(const bf16x8*)((const char*)Ks + boff);
            a = MFMA16(aq[ks], bk_, a);
        }
        s[jt] = a;
    }
    __builtin_amdgcn_s_setprio(0);

#pragma unroll
    for (int r = 0; r < 4; ++r) {
        const int i = w * 16 + quad * 4 + r;
        float m_ = -1e30f;
#pragma unroll
        for (int jt = 0; jt < 12; ++jt) {
            const int j = jt * 16 + lr;
            bool valid = (64 + i) >= j;
            if (j < 64 && nblk == 0) valid = false;
            if (j >= 128 && nblk == NB - 1) valid = false;
            const float sv = valid ? s[jt][r] * 0.125f : -1e30f;
            s[jt][r] = sv;
            m_ = fmaxf(m_, sv);
        }
#pragma unroll
        for (int st = 1; st < 16; st <<= 1)
            m_ = fmaxf(m_, __shfl_xor(m_, st, 64));
        float l_ = 0.f;
#pragma unroll
        for (int jt = 0; jt < 12; ++jt) {
            const float p = (s[jt][r] > -1e29f) ? __expf(s[jt][r] - m_) : 0.f;
            s[jt][r] = p;
            l_ += p;
        }
#pragma unroll
        for (int st = 1; st < 16; st <<= 1)
            l_ += __shfl_xor(l_, st, 64);
        const float inv = 1.f / l_;
#pragma unroll
        for (int jt = 0; jt < 12; ++jt) s[jt][r] *= inv;
    }

    __syncthreads();
#pragma unroll
    for (int r = 0; r < 4; ++r) {
        const int prow = w * 16 + quad * 4 + r;
        const int rbase = prow * 384;
        const int key = (prow & 7) << 4;
#pragma unroll
        for (int jt = 0; jt < 12; ++jt) {
            const int boff = rbase + (((jt * 16 + lr) * 2) ^ key);
            *(bf16*)((char*)Ps + boff) = (bf16)s[jt][r];
        }
    }
    __syncthreads();

    f32x4 o[4] = {};
    const int prow = w * 16 + lr;
    const int pbase = prow * 384;
    const int pkey = (prow & 7) << 4;
    __builtin_amdgcn_s_setprio(1);
#pragma unroll
    for (int kt = 0; kt < 6; ++kt) {
        bf16x8 ap = *(const bf16x8*)((const char*)Ps + pbase + ((kt * 64 + quad * 16) ^ pkey));
#pragma unroll
        for (int nt = 0; nt < 4; ++nt) {
            const int dd = nt * 16 + lr;
            const int boff = dd * (2 * VT_LD) + ((kt * 64 + quad * 16) ^ (((dd >> 3) & 7) << 4));
            bf16x8 bv_ = *(const bf16x8*)((const char*)Vt + boff);
            o[nt] = MFMA16(ap, bv_, o[nt]);
        }
    }
    __builtin_amdgcn_s_setprio(0);
#pragma unroll
    for (int nt = 0; nt < 4; ++nt) {
        const int dd = nt * 16 + lr;
#pragma unroll
        for (int r = 0; r < 4; ++r) {
            const int i = w * 16 + quad * 4 + r;
            ob[(size_t)(grow + i) * C_DIM + colbase + dd] = (bf16)o[nt][r];
        }
    }
}

// ---------------------------------------------------------------------------
// Kernel 3: output projection, 256x256 8-phase, f32 out. Grid (4, 64).
// ---------------------------------------------------------------------------
__global__ __launch_bounds__(512) void outproj256_kernel(
    const bf16* __restrict__ o, const bf16* __restrict__ Wob,
    const void* __restrict__ bo, float* __restrict__ out,
    const int* __restrict__ flag)
{
    __shared__ __align__(16) bf16 sm[65536];

    const int isf = *flag;
    const int n0 = blockIdx.x * 256;
    const int m0 = blockIdx.y * 256;

    const int tid = threadIdx.x;
    const int w = tid >> 6, lane = tid & 63;
    const int wr = w >> 2, wc = w & 3;
    const int lr = lane & 15, quad = lane >> 4;

    f32x4 acc[8][4] = {};

    GEMM256_KLOOP(o, Wob)

    // epilogue: bias + f32 out via swizzled LDS bounce, two 128-row passes
    float bb[4];
#pragma unroll
    for (int ni = 0; ni < 4; ++ni)
        bb[ni] = rd1(bo, n0 + wc * 64 + ni * 16 + lr, isf);
#pragma unroll
    for (int hh = 0; hh < 2; ++hh) {
        __syncthreads();
        if (wr == hh) {
#pragma unroll
            for (int mi = 0; mi < 8; ++mi)
#pragma unroll
                for (int ni = 0; ni < 4; ++ni)
#pragma unroll
                    for (int rr = 0; rr < 4; ++rr) {
                        const int lrow = mi * 16 + quad * 4 + rr;
                        const int col = wc * 64 + ni * 16 + lr;
                        *(float*)((char*)sm + lrow * 1024 + ((col * 4) ^ ((lrow & 7) << 4))) =
                            acc[mi][ni][rr] + bb[ni];
                    }
        }
        __syncthreads();
        const int lrow = tid >> 2, seg = (tid & 3) * 256;
        const int key = (lrow & 7) << 4;
#pragma unroll
        for (int j = 0; j < 16; ++j) {
            u32x4 vls = *(const u32x4*)((const char*)sm + lrow * 1024 + ((seg + j * 16) ^ key));
            *(u32x4*)(out + (size_t)(m0 + hh * 128 + lrow) * C_DIM + n0 + (seg >> 2) + j * 4) = vls;
        }
    }
}

extern "C" void kernel_launch(void* const* d_in, const int* in_sizes, int n_in,
                              void* d_out, int out_size, void* d_ws, size_t ws_size,
                              hipStream_t stream) {
    const void* x  = d_in[0];
    const void* Wq = d_in[1];
    const void* bq = d_in[2];
    const void* Wk = d_in[3];
    const void* bk = d_in[4];
    const void* Wv = d_in[5];
    const void* bv = d_in[6];
    const void* Wo = d_in[7];
    const void* bo = d_in[8];
    float* out = (float*)d_out;

    const int sb = (out_size + 255) / 256;
    const bool sizes_ok = (n_in == 9) &&
        in_sizes[0] == (int)QKV_ELEMS &&
        in_sizes[1] == W_ELEMS && in_sizes[2] == C_DIM &&
        in_sizes[3] == W_ELEMS && in_sizes[4] == C_DIM &&
        in_sizes[5] == W_ELEMS && in_sizes[6] == C_DIM &&
        in_sizes[7] == W_ELEMS && in_sizes[8] == C_DIM &&
        out_size == (int)QKV_ELEMS;
    if (!sizes_ok) {
        sentinel_kernel<<<sb, 256, 0, stream>>>(out, 777.0f, out_size);
        return;
    }
    // ws: flag(4KB) | q(32MB) | k(32MB) | Wb(8MB)  = 72MB + 4KB
    const size_t need = 4096 + 2 * QKV_ELEMS * sizeof(bf16) + 4 * W_ELEMS * sizeof(bf16);
    if (ws_size < need) {
        sentinel_kernel<<<sb, 256, 0, stream>>>(out, 999.0f, out_size);
        return;
    }

    int* flag = (int*)d_ws;
    bf16* q  = (bf16*)((char*)d_ws + 4096);     // attn O in-place later
    bf16* k  = q + QKV_ELEMS;
    bf16* Wb = k + QKV_ELEMS;                   // Wq|Wk|Wv|Wo bf16
    // d_out (64MB f32) parking: xb in lower 32MB, v in upper 32MB; both dead
    // before outproj's f32 stores land (same-stream kernel ordering).
    bf16* xb = (bf16*)d_out;
    bf16* v  = (bf16*)((char*)d_out + QKV_ELEMS * sizeof(bf16));

    detect_kernel<<<1, 64, 0, stream>>>((const unsigned int*)x, flag);

    cvt_kernel<<<8192 + 4 * 512, 256, 0, stream>>>(x, xb, Wq, Wk, Wv, Wo, Wb, flag);

    dim3 g1(12, 64);   // x = which*4 + nblk, y = m-block
    qkv256_kernel<<<g1, 512, 0, stream>>>(xb, Wb, bq, bk, bv, q, k, v, flag);

    attn_kernel<<<dim3(NB, BATCH * HEADS), 256, 0, stream>>>(q, k, v, q);

    dim3 g3(4, 64);
    outproj256_kernel<<<g3, 512, 0, stream>>>(q, Wb + 3 * (size_t)W_ELEMS, bo, out, flag);
}

// Round 5
// 338.302 us; speedup vs baseline: 1.2789x; 1.2789x over previous
//
#include <hip/hip_runtime.h>

typedef __bf16 bf16;
typedef __attribute__((ext_vector_type(8))) __bf16 bf16x8;
typedef __attribute__((ext_vector_type(4))) float f32x4;
typedef __attribute__((ext_vector_type(4))) unsigned int u32x4;

#define MFMA16(a, b, c) __builtin_amdgcn_mfma_f32_16x16x32_bf16(a, b, c, 0, 0, 0)

#define C_DIM 1024
#define N_TOK 4096
#define BATCH 4
#define HEADS 16
#define HD 64
#define BS 64
#define NB 64
#define M_TOT (BATCH * N_TOK)              // 16384
#define QKV_ELEMS ((size_t)M_TOT * C_DIM)  // 16777216
#define W_ELEMS (C_DIM * C_DIM)            // 1048576
#define VT_LD 200                          // V^T row stride in elems (400B rows)
#define NKT 16                             // K tiles of 64 (C_DIM/64)

// ---------------------------------------------------------------------------
// Dtype detector: flag=0 -> inputs bf16, flag=1 -> inputs f32.
// ---------------------------------------------------------------------------
__global__ void detect_kernel(const unsigned int* __restrict__ x, int* flag) {
    if (threadIdx.x == 0) {
        int cnt = 0;
        for (int i = 0; i < 256; ++i) {
            unsigned int e = (x[i] >> 7) & 0xFFu;
            cnt += (e >= 100u && e <= 140u) ? 1 : 0;
        }
        *flag = (cnt >= 192) ? 0 : 1;
    }
}

__global__ void sentinel_kernel(float* out, float val, int n) {
    int i = blockIdx.x * 256 + threadIdx.x;
    if (i < n) out[i] = val;
}

__device__ __forceinline__ bf16x8 cvt8(f32x4 a, f32x4 b) {
    bf16x8 r;
    r[0] = (bf16)a[0]; r[1] = (bf16)a[1]; r[2] = (bf16)a[2]; r[3] = (bf16)a[3];
    r[4] = (bf16)b[0]; r[5] = (bf16)b[1]; r[6] = (bf16)b[2]; r[7] = (bf16)b[3];
    return r;
}

__device__ __forceinline__ float rd1(const void* p, int i, int isf) {
    return isf ? ((const float*)p)[i] : (float)((const bf16*)p)[i];
}

// ---------------------------------------------------------------------------
// Prepass: convert x + 4 weights to bf16.
// ---------------------------------------------------------------------------
__global__ __launch_bounds__(256) void cvt_kernel(
    const void* __restrict__ x,  bf16* __restrict__ xb,
    const void* __restrict__ w0, const void* __restrict__ w1,
    const void* __restrict__ w2, const void* __restrict__ w3,
    bf16* __restrict__ wb, const int* __restrict__ flag)
{
    const int isf = *flag;
    const int bid = blockIdx.x;
    const void* src;
    bf16* dst;
    size_t off;
    if (bid < 8192) {
        src = x; dst = xb; off = (size_t)bid * 2048;
    } else {
        const int seg = (bid - 8192) >> 9;
        src = seg == 0 ? w0 : (seg == 1 ? w1 : (seg == 2 ? w2 : w3));
        dst = wb + (size_t)seg * W_ELEMS;
        off = (size_t)((bid - 8192) & 511) * 2048;
    }
    const size_t e = off + (size_t)threadIdx.x * 8;
    if (isf) {
        const float* gp = (const float*)src + e;
        *(bf16x8*)(dst + e) = cvt8(*(const f32x4*)gp, *(const f32x4*)(gp + 4));
    } else {
        *(u32x4*)(dst + e) = *(const u32x4*)((const bf16*)src + e);
    }
}

// async 16B global->LDS: lane i lands at (wave-uniform l) + i*16
__device__ __forceinline__ void gload_lds16(const bf16* g, bf16* l) {
    __builtin_amdgcn_global_load_lds(
        (const __attribute__((address_space(1))) void*)g,
        (__attribute__((address_space(3))) void*)l, 16, 0, 0);
}

// ---------------------------------------------------------------------------
// 256x256 8-phase GEMM machinery (unchanged from verified round-3 K-loop).
// ---------------------------------------------------------------------------
__device__ __forceinline__ void stageA(const bf16* __restrict__ src, bf16* lds,
                                       int h, int w, int lane, int m0, int k0) {
#pragma unroll
    for (int l = 0; l < 2; ++l) {
        const int c = w * 2 + l;                       // chunk 0..15, wave-uniform
        const int rowbase = (c >> 3) * 128 + h * 64 + (c & 7) * 8;
        const int grow = m0 + rowbase + (lane >> 3);
        const int gcol = k0 + (((lane & 7) ^ ((lane >> 3) & 7)) << 3);
        gload_lds16(src + (size_t)grow * C_DIM + gcol, lds + rowbase * 64);
    }
}
__device__ __forceinline__ void stageB(const bf16* __restrict__ src, bf16* lds,
                                       int y, int w, int lane, int n0, int k0) {
#pragma unroll
    for (int l = 0; l < 2; ++l) {
        const int c = w * 2 + l;
        const int rowbase = (c >> 2) * 64 + y * 32 + (c & 3) * 8;
        const int grow = n0 + rowbase + (lane >> 3);
        const int gcol = k0 + (((lane & 7) ^ ((lane >> 3) & 7)) << 3);
        gload_lds16(src + (size_t)grow * C_DIM + gcol, lds + rowbase * 64);
    }
}

__device__ __forceinline__ bf16x8 ldsrd(const bf16* base, int row, int kk, int quad) {
    return *(const bf16x8*)((const char*)base +
        row * 128 + ((kk * 64 + quad * 16) ^ ((row & 7) << 4)));
}

#define GEMM256_KLOOP(ASRC, BSRC)                                               \
    {                                                                           \
        bf16* Ab0 = sm;                                                         \
        bf16* Bb0 = sm + 32768;                                                 \
        stageA(ASRC, Ab0, 0, w, lane, m0, 0);                                   \
        stageA(ASRC, Ab0, 1, w, lane, m0, 0);                                   \
        stageB(BSRC, Bb0, 0, w, lane, n0, 0);                                   \
        stageB(BSRC, Bb0, 1, w, lane, n0, 0);                                   \
    }                                                                           \
    asm volatile("s_waitcnt vmcnt(0)" ::: "memory");                            \
    __syncthreads();                                                            \
    for (int t = 0; t < NKT; ++t) {                                             \
        const bool stg = (t + 1) < NKT;                                         \
        bf16* Ab = sm + (t & 1) * 16384;                                        \
        bf16* Bb = sm + 32768 + (t & 1) * 16384;                                \
        bf16* An = sm + ((t + 1) & 1) * 16384;                                  \
        bf16* Bn = sm + 32768 + ((t + 1) & 1) * 16384;                          \
        const int kn = (t + 1) * 64;                                            \
        bf16x8 af[4][2], b0[2][2], b1[2][2];                                    \
        /* phase 0: quad (mh=0, nh=0) */                                        \
        _Pragma("unroll") for (int mi = 0; mi < 4; ++mi)                        \
            _Pragma("unroll") for (int kk = 0; kk < 2; ++kk)                    \
                af[mi][kk] = ldsrd(Ab, wr * 128 + mi * 16 + lr, kk, quad);      \
        _Pragma("unroll") for (int ni = 0; ni < 2; ++ni)                        \
            _Pragma("unroll") for (int kk = 0; kk < 2; ++kk)                    \
                b0[ni][kk] = ldsrd(Bb, wc * 64 + ni * 16 + lr, kk, quad);       \
        if (stg) stageA(ASRC, An, 0, w, lane, m0, kn);                          \
        __builtin_amdgcn_s_barrier();                                           \
        __builtin_amdgcn_s_setprio(1);                                          \
        _Pragma("unroll") for (int kk = 0; kk < 2; ++kk)                        \
            _Pragma("unroll") for (int mi = 0; mi < 4; ++mi)                    \
                _Pragma("unroll") for (int ni = 0; ni < 2; ++ni)                \
                    acc[mi][ni] = MFMA16(af[mi][kk], b0[ni][kk], acc[mi][ni]);  \
        __builtin_amdgcn_s_setprio(0);                                          \
        if (stg) asm volatile("s_waitcnt vmcnt(4)" ::: "memory");               \
        else     asm volatile("s_waitcnt vmcnt(2)" ::: "memory");               \
        __builtin_amdgcn_s_barrier();                                           \
        /* phase 1: quad (mh=0, nh=1) */                                        \
        _Pragma("unroll") for (int ni = 0; ni < 2; ++ni)                        \
            _Pragma("unroll") for (int kk = 0; kk < 2; ++kk)                    \
                b1[ni][kk] = ldsrd(Bb, wc * 64 + 32 + ni * 16 + lr, kk, quad);  \
        if (stg) stageB(BSRC, Bn, 0, w, lane, n0, kn);                          \
        __builtin_amdgcn_s_barrier();                                           \
        __builtin_amdgcn_s_setprio(1);                                          \
        _Pragma("unroll") for (int kk = 0; kk < 2; ++kk)                        \
            _Pragma("unroll") for (int mi = 0; mi < 4; ++mi)                    \
                _Pragma("unroll") for (int ni = 0; ni < 2; ++ni)                \
                    acc[mi][2 + ni] = MFMA16(af[mi][kk], b1[ni][kk], acc[mi][2 + ni]); \
        __builtin_amdgcn_s_setprio(0);                                          \
        if (stg) asm volatile("s_waitcnt vmcnt(4)" ::: "memory");               \
        else     asm volatile("s_waitcnt vmcnt(0)" ::: "memory");               \
        __builtin_amdgcn_s_barrier();                                           \
        /* phase 2: quad (mh=1, nh=0) */                                        \
        _Pragma("unroll") for (int mi = 0; mi < 4; ++mi)                        \
            _Pragma("unroll") for (int kk = 0; kk < 2; ++kk)                    \
                af[mi][kk] = ldsrd(Ab, wr * 128 + 64 + mi * 16 + lr, kk, quad); \
        if (stg) stageB(BSRC, Bn, 1, w, lane, n0, kn);                          \
        __builtin_amdgcn_s_barrier();                                           \
        __builtin_amdgcn_s_setprio(1);                                          \
        _Pragma("unroll") for (int kk = 0; kk < 2; ++kk)                        \
            _Pragma("unroll") for (int mi = 0; mi < 4; ++mi)                    \
                _Pragma("unroll") for (int ni = 0; ni < 2; ++ni)                \
                    acc[4 + mi][ni] = MFMA16(af[mi][kk], b0[ni][kk], acc[4 + mi][ni]); \
        __builtin_amdgcn_s_setprio(0);                                          \
        __builtin_amdgcn_s_barrier();                                           \
        /* phase 3: quad (mh=1, nh=1) */                                        \
        if (stg) stageA(ASRC, An, 1, w, lane, m0, kn);                          \
        __builtin_amdgcn_s_barrier();                                           \
        __builtin_amdgcn_s_setprio(1);                                          \
        _Pragma("unroll") for (int kk = 0; kk < 2; ++kk)                        \
            _Pragma("unroll") for (int mi = 0; mi < 4; ++mi)                    \
                _Pragma("unroll") for (int ni = 0; ni < 2; ++ni)                \
                    acc[4 + mi][2 + ni] = MFMA16(af[mi][kk], b1[ni][kk], acc[4 + mi][2 + ni]); \
        __builtin_amdgcn_s_setprio(0);                                          \
        if (stg) asm volatile("s_waitcnt vmcnt(4)" ::: "memory");               \
        __builtin_amdgcn_s_barrier();                                           \
    }

// ---------------------------------------------------------------------------
// Kernel 1: fused QKV projection, 256x256 8-phase. 1D grid 768, XCD-swizzled:
// work = (bid&7)*96 + bid>>3 -> XCD x owns 8 whole A-panels (12 works each).
// ---------------------------------------------------------------------------
__global__ __launch_bounds__(512) void qkv256_kernel(
    const bf16* __restrict__ xb, const bf16* __restrict__ wb,
    const void* __restrict__ bq, const void* __restrict__ bk,
    const void* __restrict__ bv,
    bf16* __restrict__ qo, bf16* __restrict__ ko, bf16* __restrict__ vo,
    const int* __restrict__ flag)
{
    __shared__ __align__(16) bf16 sm[65536];   // 128 KiB: 2 dbuf x (A 32K + B 32K)

    const int isf = *flag;
    const int bid = blockIdx.x;
    const int work = (bid & 7) * 96 + (bid >> 3);   // bijective, 768 % 8 == 0
    const int y = work / 12, xx = work % 12;
    const int which = xx >> 2;
    const int n0 = (xx & 3) * 256;
    const int m0 = y * 256;
    const bf16* W  = wb + (size_t)which * W_ELEMS;
    const void* bia = which == 0 ? bq : (which == 1 ? bk : bv);
    bf16* dst       = which == 0 ? qo : (which == 1 ? ko : vo);

    const int tid = threadIdx.x;
    const int w = tid >> 6, lane = tid & 63;
    const int wr = w >> 2, wc = w & 3;               // 2M x 4N waves
    const int lr = lane & 15, quad = lane >> 4;

    f32x4 acc[8][4] = {};

    GEMM256_KLOOP(xb, W)

    // epilogue: bias + bf16 pack via swizzled LDS bounce
    __syncthreads();
    float bb[4];
#pragma unroll
    for (int ni = 0; ni < 4; ++ni)
        bb[ni] = rd1(bia, n0 + wc * 64 + ni * 16 + lr, isf);
#pragma unroll
    for (int mi = 0; mi < 8; ++mi)
#pragma unroll
        for (int ni = 0; ni < 4; ++ni)
#pragma unroll
            for (int rr = 0; rr < 4; ++rr) {
                const int row = wr * 128 + mi * 16 + quad * 4 + rr;
                const int col = wc * 64 + ni * 16 + lr;
                *(bf16*)((char*)sm + row * 512 + ((col * 2) ^ ((row & 7) << 4))) =
                    (bf16)(acc[mi][ni][rr] + bb[ni]);
            }
    __syncthreads();
    // store: chunk-linear -> each wave writes 2 rows x 512B contiguous
#pragma unroll
    for (int j = 0; j < 16; ++j) {
        const int idx = j * 512 + tid;
        const int row = idx >> 5, ch = idx & 31;
        u32x4 vls = *(const u32x4*)((const char*)sm + row * 512 + ((ch * 16) ^ ((row & 7) << 4)));
        *(u32x4*)(dst + (size_t)(m0 + row) * C_DIM + n0 + ch * 8) = vls;
    }
}

// ---------------------------------------------------------------------------
// Kernel 2: block-sparse attention via MFMA (verified round-2 version).
// ---------------------------------------------------------------------------
__global__ __launch_bounds__(256) void attn_kernel(
    const bf16* qb, const bf16* __restrict__ kb,
    const bf16* __restrict__ vb, bf16* ob)
{
    __shared__ __align__(16) bf16 sh[12288 + 64 * VT_LD];
    bf16* Ks = sh;               // 192x64, rows of 128B, col bytes ^ (row&7)<<4
    bf16* Ps = sh;               // 64x192, overlays Ks after phase 1
    bf16* Vt = sh + 12288;       // 64 x VT_LD, col bytes ^ ((dd>>3)&7)<<4

    const int nblk = blockIdx.x, bh = blockIdx.y, tid = threadIdx.x;
    const int b = bh >> 4, h = bh & 15;
    const int w = tid >> 6, lane = tid & 63;
    const int lr = lane & 15, quad = lane >> 4;
    const int grow = b * N_TOK + nblk * BS;
    const int colbase = h * HD;

    bf16x8 aq[2];
#pragma unroll
    for (int ks = 0; ks < 2; ++ks)
        aq[ks] = *(const bf16x8*)(qb + (size_t)(grow + w * 16 + lr) * C_DIM
                                  + colbase + ks * 32 + quad * 8);

    for (int wbk = 0; wbk < 3; ++wbk) {
        const int gb = nblk - 1 + wbk;
        const bool ok = (gb >= 0 && gb < NB);
#pragma unroll
        for (int p = 0; p < 2; ++p) {
            const int e = (p * 256 + tid) * 8;
            const int row = e >> 6, col = e & 63;
            const int boff = (wbk * 64 + row) * 128 + ((col * 2) ^ ((row & 7) << 4));
            u32x4 val = {};
            if (ok)
                val = *(const u32x4*)(kb + (size_t)(b * N_TOK + gb * BS + row) * C_DIM + colbase + col);
            *(u32x4*)((char*)Ks + boff) = val;
        }
    }
#pragma unroll
    for (int t = 0; t < 6; ++t) {
        const int e8 = (t * 256 + tid) * 8;
        const int kk = e8 >> 6, dd0 = e8 & 63;
        const int gb = nblk - 1 + (kk >> 6);
        bf16x8 vv = {};
        if (gb >= 0 && gb < NB)
            vv = *(const bf16x8*)(vb + (size_t)(b * N_TOK + gb * BS + (kk & 63)) * C_DIM + colbase + dd0);
        const int key = ((dd0 >> 3) & 7) << 4;
#pragma unroll
        for (int i = 0; i < 8; ++i) {
            const int boff = (dd0 + i) * (2 * VT_LD) + ((kk * 2) ^ key);
            *(bf16*)((char*)Vt + boff) = vv[i];
        }
    }
    __syncthreads();

    f32x4 s[12];
    __builtin_amdgcn_s_setprio(1);
#pragma unroll
    for (int jt = 0; jt < 12; ++jt) {
        f32x4 a = {};
#pragma unroll
        for (int ks = 0; ks < 2; ++ks) {
            const int boff = (jt * 16 + lr) * 128 + ((ks * 64 + quad * 16) ^ ((lr & 7) << 4));
            bf16x8 bk_ = *(const bf16x8*)((const char*)Ks + boff);
            a = MFMA16(aq[ks], bk_, a);
        }
        s[jt] = a;
    }
    __builtin_amdgcn_s_setprio(0);

#pragma unroll
    for (int r = 0; r < 4; ++r) {
        const int i = w * 16 + quad * 4 + r;
        float m_ = -1e30f;
#pragma unroll
        for (int jt = 0; jt < 12; ++jt) {
            const int j = jt * 16 + lr;
            bool valid = (64 + i) >= j;
            if (j < 64 && nblk == 0) valid = false;
            if (j >= 128 && nblk == NB - 1) valid = false;
            const float sv = valid ? s[jt][r] * 0.125f : -1e30f;
            s[jt][r] = sv;
            m_ = fmaxf(m_, sv);
        }
#pragma unroll
        for (int st = 1; st < 16; st <<= 1)
            m_ = fmaxf(m_, __shfl_xor(m_, st, 64));
        float l_ = 0.f;
#pragma unroll
        for (int jt = 0; jt < 12; ++jt) {
            const float p = (s[jt][r] > -1e29f) ? __expf(s[jt][r] - m_) : 0.f;
            s[jt][r] = p;
            l_ += p;
        }
#pragma unroll
        for (int st = 1; st < 16; st <<= 1)
            l_ += __shfl_xor(l_, st, 64);
        const float inv = 1.f / l_;
#pragma unroll
        for (int jt = 0; jt < 12; ++jt) s[jt][r] *= inv;
    }

    __syncthreads();
#pragma unroll
    for (int r = 0; r < 4; ++r) {
        const int prow = w * 16 + quad * 4 + r;
        const int rbase = prow * 384;
        const int key = (prow & 7) << 4;
#pragma unroll
        for (int jt = 0; jt < 12; ++jt) {
            const int boff = rbase + (((jt * 16 + lr) * 2) ^ key);
            *(bf16*)((char*)Ps + boff) = (bf16)s[jt][r];
        }
    }
    __syncthreads();

    f32x4 o[4] = {};
    const int prow = w * 16 + lr;
    const int pbase = prow * 384;
    const int pkey = (prow & 7) << 4;
    __builtin_amdgcn_s_setprio(1);
#pragma unroll
    for (int kt = 0; kt < 6; ++kt) {
        bf16x8 ap = *(const bf16x8*)((const char*)Ps + pbase + ((kt * 64 + quad * 16) ^ pkey));
#pragma unroll
        for (int nt = 0; nt < 4; ++nt) {
            const int dd = nt * 16 + lr;
            const int boff = dd * (2 * VT_LD) + ((kt * 64 + quad * 16) ^ (((dd >> 3) & 7) << 4));
            bf16x8 bv_ = *(const bf16x8*)((const char*)Vt + boff);
            o[nt] = MFMA16(ap, bv_, o[nt]);
        }
    }
    __builtin_amdgcn_s_setprio(0);
#pragma unroll
    for (int nt = 0; nt < 4; ++nt) {
        const int dd = nt * 16 + lr;
#pragma unroll
        for (int r = 0; r < 4; ++r) {
            const int i = w * 16 + quad * 4 + r;
            ob[(size_t)(grow + i) * C_DIM + colbase + dd] = (bf16)o[nt][r];
        }
    }
}

// ---------------------------------------------------------------------------
// Kernel 3: output projection, 256x256 8-phase, f32 out. 1D grid 256,
// XCD-swizzled: work = (bid&7)*32 + bid>>3 -> XCD x owns 8 whole A-panels.
// ---------------------------------------------------------------------------
__global__ __launch_bounds__(512) void outproj256_kernel(
    const bf16* __restrict__ o, const bf16* __restrict__ Wob,
    const void* __restrict__ bo, float* __restrict__ out,
    const int* __restrict__ flag)
{
    __shared__ __align__(16) bf16 sm[65536];

    const int isf = *flag;
    const int bid = blockIdx.x;
    const int work = (bid & 7) * 32 + (bid >> 3);   // bijective, 256 % 8 == 0
    const int n0 = (work & 3) * 256;
    const int m0 = (work >> 2) * 256;

    const int tid = threadIdx.x;
    const int w = tid >> 6, lane = tid & 63;
    const int wr = w >> 2, wc = w & 3;
    const int lr = lane & 15, quad = lane >> 4;

    f32x4 acc[8][4] = {};

    GEMM256_KLOOP(o, Wob)

    // epilogue: bias + f32 out via swizzled LDS bounce, two 128-row passes
    float bb[4];
#pragma unroll
    for (int ni = 0; ni < 4; ++ni)
        bb[ni] = rd1(bo, n0 + wc * 64 + ni * 16 + lr, isf);
#pragma unroll
    for (int hh = 0; hh < 2; ++hh) {
        __syncthreads();
        if (wr == hh) {
#pragma unroll
            for (int mi = 0; mi < 8; ++mi)
#pragma unroll
                for (int ni = 0; ni < 4; ++ni)
#pragma unroll
                    for (int rr = 0; rr < 4; ++rr) {
                        const int lrow = mi * 16 + quad * 4 + rr;
                        const int col = wc * 64 + ni * 16 + lr;
                        *(float*)((char*)sm + lrow * 1024 + ((col * 4) ^ ((lrow & 7) << 4))) =
                            acc[mi][ni][rr] + bb[ni];
                    }
        }
        __syncthreads();
        // store: chunk-linear -> each wave writes one full row (1024B contiguous)
#pragma unroll
        for (int j = 0; j < 16; ++j) {
            const int idx = j * 512 + tid;
            const int row = idx >> 6, ch = idx & 63;
            u32x4 vls = *(const u32x4*)((const char*)sm + row * 1024 + ((ch * 16) ^ ((row & 7) << 4)));
            *(u32x4*)(out + (size_t)(m0 + hh * 128 + row) * C_DIM + n0 + ch * 4) = vls;
        }
    }
}

extern "C" void kernel_launch(void* const* d_in, const int* in_sizes, int n_in,
                              void* d_out, int out_size, void* d_ws, size_t ws_size,
                              hipStream_t stream) {
    const void* x  = d_in[0];
    const void* Wq = d_in[1];
    const void* bq = d_in[2];
    const void* Wk = d_in[3];
    const void* bk = d_in[4];
    const void* Wv = d_in[5];
    const void* bv = d_in[6];
    const void* Wo = d_in[7];
    const void* bo = d_in[8];
    float* out = (float*)d_out;

    const int sb = (out_size + 255) / 256;
    const bool sizes_ok = (n_in == 9) &&
        in_sizes[0] == (int)QKV_ELEMS &&
        in_sizes[1] == W_ELEMS && in_sizes[2] == C_DIM &&
        in_sizes[3] == W_ELEMS && in_sizes[4] == C_DIM &&
        in_sizes[5] == W_ELEMS && in_sizes[6] == C_DIM &&
        in_sizes[7] == W_ELEMS && in_sizes[8] == C_DIM &&
        out_size == (int)QKV_ELEMS;
    if (!sizes_ok) {
        sentinel_kernel<<<sb, 256, 0, stream>>>(out, 777.0f, out_size);
        return;
    }
    // ws: flag(4KB) | q(32MB) | k(32MB) | Wb(8MB)  = 72MB + 4KB
    const size_t need = 4096 + 2 * QKV_ELEMS * sizeof(bf16) + 4 * W_ELEMS * sizeof(bf16);
    if (ws_size < need) {
        sentinel_kernel<<<sb, 256, 0, stream>>>(out, 999.0f, out_size);
        return;
    }

    int* flag = (int*)d_ws;
    bf16* q  = (bf16*)((char*)d_ws + 4096);     // attn O in-place later
    bf16* k  = q + QKV_ELEMS;
    bf16* Wb = k + QKV_ELEMS;                   // Wq|Wk|Wv|Wo bf16
    // d_out (64MB f32) parking: xb in lower 32MB, v in upper 32MB; both dead
    // before outproj's f32 stores land (same-stream kernel ordering).
    bf16* xb = (bf16*)d_out;
    bf16* v  = (bf16*)((char*)d_out + QKV_ELEMS * sizeof(bf16));

    detect_kernel<<<1, 64, 0, stream>>>((const unsigned int*)x, flag);

    cvt_kernel<<<8192 + 4 * 512, 256, 0, stream>>>(x, xb, Wq, Wk, Wv, Wo, Wb, flag);

    qkv256_kernel<<<768, 512, 0, stream>>>(xb, Wb, bq, bk, bv, q, k, v, flag);

    attn_kernel<<<dim3(NB, BATCH * HEADS), 256, 0, stream>>>(q, k, v, q);

    outproj256_kernel<<<256, 512, 0, stream>>>(q, Wb + 3 * (size_t)W_ELEMS, bo, out, flag);
}

// Round 6
// 310.330 us; speedup vs baseline: 1.3942x; 1.0901x over previous
//
#include <hip/hip_runtime.h>

typedef __bf16 bf16;
typedef __attribute__((ext_vector_type(8))) __bf16 bf16x8;
typedef __attribute__((ext_vector_type(4))) float f32x4;
typedef __attribute__((ext_vector_type(4))) unsigned int u32x4;

#define MFMA16(a, b, c) __builtin_amdgcn_mfma_f32_16x16x32_bf16(a, b, c, 0, 0, 0)

#define C_DIM 1024
#define N_TOK 4096
#define BATCH 4
#define HEADS 16
#define HD 64
#define BS 64
#define NB 64
#define M_TOT (BATCH * N_TOK)              // 16384
#define QKV_ELEMS ((size_t)M_TOT * C_DIM)  // 16777216
#define W_ELEMS (C_DIM * C_DIM)            // 1048576
#define VT_LD 200                          // V^T row stride in elems (400B rows)
#define NKT 16                             // K tiles of 64 (C_DIM/64)

// ---------------------------------------------------------------------------
// Dtype detector: flag=0 -> inputs bf16, flag=1 -> inputs f32.
// Wave-parallel: 64 lanes x 4 words (was 256 serial loads on one thread).
// ---------------------------------------------------------------------------
__global__ void detect_kernel(const unsigned int* __restrict__ x, int* flag) {
    const int lane = threadIdx.x & 63;
    int cnt = 0;
#pragma unroll
    for (int i = 0; i < 4; ++i) {
        const unsigned int e = (x[lane * 4 + i] >> 7) & 0xFFu;
        cnt += (e >= 100u && e <= 140u) ? 1 : 0;
    }
#pragma unroll
    for (int st = 1; st < 64; st <<= 1) cnt += __shfl_xor(cnt, st, 64);
    if (threadIdx.x == 0) *flag = (cnt >= 192) ? 0 : 1;
}

__global__ void sentinel_kernel(float* out, float val, int n) {
    int i = blockIdx.x * 256 + threadIdx.x;
    if (i < n) out[i] = val;
}

__device__ __forceinline__ bf16x8 cvt8(f32x4 a, f32x4 b) {
    bf16x8 r;
    r[0] = (bf16)a[0]; r[1] = (bf16)a[1]; r[2] = (bf16)a[2]; r[3] = (bf16)a[3];
    r[4] = (bf16)b[0]; r[5] = (bf16)b[1]; r[6] = (bf16)b[2]; r[7] = (bf16)b[3];
    return r;
}

__device__ __forceinline__ float rd1(const void* p, int i, int isf) {
    return isf ? ((const float*)p)[i] : (float)((const bf16*)p)[i];
}

// ---------------------------------------------------------------------------
// Prepass: convert x + 4 weights to bf16.
// ---------------------------------------------------------------------------
__global__ __launch_bounds__(256) void cvt_kernel(
    const void* __restrict__ x,  bf16* __restrict__ xb,
    const void* __restrict__ w0, const void* __restrict__ w1,
    const void* __restrict__ w2, const void* __restrict__ w3,
    bf16* __restrict__ wb, const int* __restrict__ flag)
{
    const int isf = *flag;
    const int bid = blockIdx.x;
    const void* src;
    bf16* dst;
    size_t off;
    if (bid < 8192) {
        src = x; dst = xb; off = (size_t)bid * 2048;
    } else {
        const int seg = (bid - 8192) >> 9;
        src = seg == 0 ? w0 : (seg == 1 ? w1 : (seg == 2 ? w2 : w3));
        dst = wb + (size_t)seg * W_ELEMS;
        off = (size_t)((bid - 8192) & 511) * 2048;
    }
    const size_t e = off + (size_t)threadIdx.x * 8;
    if (isf) {
        const float* gp = (const float*)src + e;
        *(bf16x8*)(dst + e) = cvt8(*(const f32x4*)gp, *(const f32x4*)(gp + 4));
    } else {
        *(u32x4*)(dst + e) = *(const u32x4*)((const bf16*)src + e);
    }
}

// async 16B global->LDS: lane i lands at (wave-uniform l) + i*16
__device__ __forceinline__ void gload_lds16(const bf16* g, bf16* l) {
    __builtin_amdgcn_global_load_lds(
        (const __attribute__((address_space(1))) void*)g,
        (__attribute__((address_space(3))) void*)l, 16, 0, 0);
}

// ---------------------------------------------------------------------------
// 256x256 8-phase GEMM machinery (unchanged from verified round-5 K-loop).
// ---------------------------------------------------------------------------
__device__ __forceinline__ void stageA(const bf16* __restrict__ src, bf16* lds,
                                       int h, int w, int lane, int m0, int k0) {
#pragma unroll
    for (int l = 0; l < 2; ++l) {
        const int c = w * 2 + l;                       // chunk 0..15, wave-uniform
        const int rowbase = (c >> 3) * 128 + h * 64 + (c & 7) * 8;
        const int grow = m0 + rowbase + (lane >> 3);
        const int gcol = k0 + (((lane & 7) ^ ((lane >> 3) & 7)) << 3);
        gload_lds16(src + (size_t)grow * C_DIM + gcol, lds + rowbase * 64);
    }
}
__device__ __forceinline__ void stageB(const bf16* __restrict__ src, bf16* lds,
                                       int y, int w, int lane, int n0, int k0) {
#pragma unroll
    for (int l = 0; l < 2; ++l) {
        const int c = w * 2 + l;
        const int rowbase = (c >> 2) * 64 + y * 32 + (c & 3) * 8;
        const int grow = n0 + rowbase + (lane >> 3);
        const int gcol = k0 + (((lane & 7) ^ ((lane >> 3) & 7)) << 3);
        gload_lds16(src + (size_t)grow * C_DIM + gcol, lds + rowbase * 64);
    }
}

__device__ __forceinline__ bf16x8 ldsrd(const bf16* base, int row, int kk, int quad) {
    return *(const bf16x8*)((const char*)base +
        row * 128 + ((kk * 64 + quad * 16) ^ ((row & 7) << 4)));
}

#define GEMM256_KLOOP(ASRC, BSRC)                                               \
    {                                                                           \
        bf16* Ab0 = sm;                                                         \
        bf16* Bb0 = sm + 32768;                                                 \
        stageA(ASRC, Ab0, 0, w, lane, m0, 0);                                   \
        stageA(ASRC, Ab0, 1, w, lane, m0, 0);                                   \
        stageB(BSRC, Bb0, 0, w, lane, n0, 0);                                   \
        stageB(BSRC, Bb0, 1, w, lane, n0, 0);                                   \
    }                                                                           \
    asm volatile("s_waitcnt vmcnt(0)" ::: "memory");                            \
    __syncthreads();                                                            \
    for (int t = 0; t < NKT; ++t) {                                             \
        const bool stg = (t + 1) < NKT;                                         \
        bf16* Ab = sm + (t & 1) * 16384;                                        \
        bf16* Bb = sm + 32768 + (t & 1) * 16384;                                \
        bf16* An = sm + ((t + 1) & 1) * 16384;                                  \
        bf16* Bn = sm + 32768 + ((t + 1) & 1) * 16384;                          \
        const int kn = (t + 1) * 64;                                            \
        bf16x8 af[4][2], b0[2][2], b1[2][2];                                    \
        /* phase 0: quad (mh=0, nh=0) */                                        \
        _Pragma("unroll") for (int mi = 0; mi < 4; ++mi)                        \
            _Pragma("unroll") for (int kk = 0; kk < 2; ++kk)                    \
                af[mi][kk] = ldsrd(Ab, wr * 128 + mi * 16 + lr, kk, quad);      \
        _Pragma("unroll") for (int ni = 0; ni < 2; ++ni)                        \
            _Pragma("unroll") for (int kk = 0; kk < 2; ++kk)                    \
                b0[ni][kk] = ldsrd(Bb, wc * 64 + ni * 16 + lr, kk, quad);       \
        if (stg) stageA(ASRC, An, 0, w, lane, m0, kn);                          \
        __builtin_amdgcn_s_barrier();                                           \
        __builtin_amdgcn_s_setprio(1);                                          \
        _Pragma("unroll") for (int kk = 0; kk < 2; ++kk)                        \
            _Pragma("unroll") for (int mi = 0; mi < 4; ++mi)                    \
                _Pragma("unroll") for (int ni = 0; ni < 2; ++ni)                \
                    acc[mi][ni] = MFMA16(af[mi][kk], b0[ni][kk], acc[mi][ni]);  \
        __builtin_amdgcn_s_setprio(0);                                          \
        if (stg) asm volatile("s_waitcnt vmcnt(4)" ::: "memory");               \
        else     asm volatile("s_waitcnt vmcnt(2)" ::: "memory");               \
        __builtin_amdgcn_s_barrier();                                           \
        /* phase 1: quad (mh=0, nh=1) */                                        \
        _Pragma("unroll") for (int ni = 0; ni < 2; ++ni)                        \
            _Pragma("unroll") for (int kk = 0; kk < 2; ++kk)                    \
                b1[ni][kk] = ldsrd(Bb, wc * 64 + 32 + ni * 16 + lr, kk, quad);  \
        if (stg) stageB(BSRC, Bn, 0, w, lane, n0, kn);                          \
        __builtin_amdgcn_s_barrier();                                           \
        __builtin_amdgcn_s_setprio(1);                                          \
        _Pragma("unroll") for (int kk = 0; kk < 2; ++kk)                        \
            _Pragma("unroll") for (int mi = 0; mi < 4; ++mi)                    \
                _Pragma("unroll") for (int ni = 0; ni < 2; ++ni)                \
                    acc[mi][2 + ni] = MFMA16(af[mi][kk], b1[ni][kk], acc[mi][2 + ni]); \
        __builtin_amdgcn_s_setprio(0);                                          \
        if (stg) asm volatile("s_waitcnt vmcnt(4)" ::: "memory");               \
        else     asm volatile("s_waitcnt vmcnt(0)" ::: "memory");               \
        __builtin_amdgcn_s_barrier();                                           \
        /* phase 2: quad (mh=1, nh=0) */                                        \
        _Pragma("unroll") for (int mi = 0; mi < 4; ++mi)                        \
            _Pragma("unroll") for (int kk = 0; kk < 2; ++kk)                    \
                af[mi][kk] = ldsrd(Ab, wr * 128 + 64 + mi * 16 + lr, kk, quad); \
        if (stg) stageB(BSRC, Bn, 1, w, lane, n0, kn);                          \
        __builtin_amdgcn_s_barrier();                                           \
        __builtin_amdgcn_s_setprio(1);                                          \
        _Pragma("unroll") for (int kk = 0; kk < 2; ++kk)                        \
            _Pragma("unroll") for (int mi = 0; mi < 4; ++mi)                    \
                _Pragma("unroll") for (int ni = 0; ni < 2; ++ni)                \
                    acc[4 + mi][ni] = MFMA16(af[mi][kk], b0[ni][kk], acc[4 + mi][ni]); \
        __builtin_amdgcn_s_setprio(0);                                          \
        __builtin_amdgcn_s_barrier();                                           \
        /* phase 3: quad (mh=1, nh=1) */                                        \
        if (stg) stageA(ASRC, An, 1, w, lane, m0, kn);                          \
        __builtin_amdgcn_s_barrier();                                           \
        __builtin_amdgcn_s_setprio(1);                                          \
        _Pragma("unroll") for (int kk = 0; kk < 2; ++kk)                        \
            _Pragma("unroll") for (int mi = 0; mi < 4; ++mi)                    \
                _Pragma("unroll") for (int ni = 0; ni < 2; ++ni)                \
                    acc[4 + mi][2 + ni] = MFMA16(af[mi][kk], b1[ni][kk], acc[4 + mi][2 + ni]); \
        __builtin_amdgcn_s_setprio(0);                                          \
        if (stg) asm volatile("s_waitcnt vmcnt(4)" ::: "memory");               \
        __builtin_amdgcn_s_barrier();                                           \
    }

// ---------------------------------------------------------------------------
// Kernel 1: fused QKV projection, 256x256 8-phase. 1D grid 768, XCD-swizzled:
// work = (bid&7)*96 + bid>>3 -> XCD x owns 8 whole A-panels (12 works each).
// ---------------------------------------------------------------------------
__global__ __launch_bounds__(512) void qkv256_kernel(
    const bf16* __restrict__ xb, const bf16* __restrict__ wb,
    const void* __restrict__ bq, const void* __restrict__ bk,
    const void* __restrict__ bv,
    bf16* __restrict__ qo, bf16* __restrict__ ko, bf16* __restrict__ vo,
    const int* __restrict__ flag)
{
    __shared__ __align__(16) bf16 sm[65536];   // 128 KiB: 2 dbuf x (A 32K + B 32K)

    const int isf = *flag;
    const int bid = blockIdx.x;
    const int work = (bid & 7) * 96 + (bid >> 3);   // bijective, 768 % 8 == 0
    const int y = work / 12, xx = work % 12;
    const int which = xx >> 2;
    const int n0 = (xx & 3) * 256;
    const int m0 = y * 256;
    const bf16* W  = wb + (size_t)which * W_ELEMS;
    const void* bia = which == 0 ? bq : (which == 1 ? bk : bv);
    bf16* dst       = which == 0 ? qo : (which == 1 ? ko : vo);

    const int tid = threadIdx.x;
    const int w = tid >> 6, lane = tid & 63;
    const int wr = w >> 2, wc = w & 3;               // 2M x 4N waves
    const int lr = lane & 15, quad = lane >> 4;

    f32x4 acc[8][4] = {};

    GEMM256_KLOOP(xb, W)

    // epilogue: bias + bf16 pack via swizzled LDS bounce
    __syncthreads();
    float bb[4];
#pragma unroll
    for (int ni = 0; ni < 4; ++ni)
        bb[ni] = rd1(bia, n0 + wc * 64 + ni * 16 + lr, isf);
#pragma unroll
    for (int mi = 0; mi < 8; ++mi)
#pragma unroll
        for (int ni = 0; ni < 4; ++ni)
#pragma unroll
            for (int rr = 0; rr < 4; ++rr) {
                const int row = wr * 128 + mi * 16 + quad * 4 + rr;
                const int col = wc * 64 + ni * 16 + lr;
                *(bf16*)((char*)sm + row * 512 + ((col * 2) ^ ((row & 7) << 4))) =
                    (bf16)(acc[mi][ni][rr] + bb[ni]);
            }
    __syncthreads();
    // store: chunk-linear -> each wave writes 2 rows x 512B contiguous
#pragma unroll
    for (int j = 0; j < 16; ++j) {
        const int idx = j * 512 + tid;
        const int row = idx >> 5, ch = idx & 31;
        u32x4 vls = *(const u32x4*)((const char*)sm + row * 512 + ((ch * 16) ^ ((row & 7) << 4)));
        *(u32x4*)(dst + (size_t)(m0 + row) * C_DIM + n0 + ch * 8) = vls;
    }
}

// ---------------------------------------------------------------------------
// Kernel 2: block-sparse attention via MFMA. 1D grid 4096, XCD-swizzled
// (work = (bid&7)*512 + bid>>3 -> XCD x owns 8 whole bh rows; sliding K/V
// windows then reuse within one XCD's L2). T14 async-STAGE: V global loads
// issued first, held in regs through QK^T+softmax, written to Vt late.
// ---------------------------------------------------------------------------
__global__ __launch_bounds__(256) void attn_kernel(
    const bf16* qb, const bf16* __restrict__ kb,
    const bf16* __restrict__ vb, bf16* ob)
{
    __shared__ __align__(16) bf16 sh[12288 + 64 * VT_LD];
    bf16* Ks = sh;               // 192x64, rows of 128B, col bytes ^ (row&7)<<4
    bf16* Ps = sh;               // 64x192, overlays Ks after phase 1
    bf16* Vt = sh + 12288;       // 64 x VT_LD, col bytes ^ ((dd>>3)&7)<<4

    const int bid = blockIdx.x;
    const int work = (bid & 7) * 512 + (bid >> 3);   // bijective, 4096 % 8 == 0
    const int nblk = work & 63, bh = work >> 6;
    const int tid = threadIdx.x;
    const int b = bh >> 4, h = bh & 15;
    const int w = tid >> 6, lane = tid & 63;
    const int lr = lane & 15, quad = lane >> 4;
    const int grow = b * N_TOK + nblk * BS;
    const int colbase = h * HD;

    // ---- T14: issue V global loads FIRST; consumed after softmax ----
    bf16x8 vv[6];
#pragma unroll
    for (int t = 0; t < 6; ++t) {
        const int e8 = (t * 256 + tid) * 8;
        const int kk = e8 >> 6, dd0 = e8 & 63;
        const int gb = nblk - 1 + (kk >> 6);
        bf16x8 z = {};
        vv[t] = z;
        if (gb >= 0 && gb < NB)
            vv[t] = *(const bf16x8*)(vb + (size_t)(b * N_TOK + gb * BS + (kk & 63)) * C_DIM + colbase + dd0);
    }

    // ---- Q fragments straight from global (wave w owns q-rows w*16..+15) ----
    bf16x8 aq[2];
#pragma unroll
    for (int ks = 0; ks < 2; ++ks)
        aq[ks] = *(const bf16x8*)(qb + (size_t)(grow + w * 16 + lr) * C_DIM
                                  + colbase + ks * 32 + quad * 8);

    // ---- stage K window (3 blocks; zero-fill out-of-range), swizzled ----
    for (int wbk = 0; wbk < 3; ++wbk) {
        const int gb = nblk - 1 + wbk;
        const bool ok = (gb >= 0 && gb < NB);
#pragma unroll
        for (int p = 0; p < 2; ++p) {
            const int e = (p * 256 + tid) * 8;
            const int row = e >> 6, col = e & 63;
            const int boff = (wbk * 64 + row) * 128 + ((col * 2) ^ ((row & 7) << 4));
            u32x4 val = {};
            if (ok)
                val = *(const u32x4*)(kb + (size_t)(b * N_TOK + gb * BS + row) * C_DIM + colbase + col);
            *(u32x4*)((char*)Ks + boff) = val;
        }
    }
    __syncthreads();

    // ---- phase 1: S = Q K^T ; wave w owns q-rows w*16..+15 ----
    f32x4 s[12];
    __builtin_amdgcn_s_setprio(1);
#pragma unroll
    for (int jt = 0; jt < 12; ++jt) {
        f32x4 a = {};
#pragma unroll
        for (int ks = 0; ks < 2; ++ks) {
            const int boff = (jt * 16 + lr) * 128 + ((ks * 64 + quad * 16) ^ ((lr & 7) << 4));
            bf16x8 bk_ = *(const bf16x8*)((const char*)Ks + boff);
            a = MFMA16(aq[ks], bk_, a);
        }
        s[jt] = a;
    }
    __builtin_amdgcn_s_setprio(0);

    // ---- mask + softmax; C-layout: row = quad*4+r, col = jt*16+lr ----
#pragma unroll
    for (int r = 0; r < 4; ++r) {
        const int i = w * 16 + quad * 4 + r;
        float m_ = -1e30f;
#pragma unroll
        for (int jt = 0; jt < 12; ++jt) {
            const int j = jt * 16 + lr;
            bool valid = (64 + i) >= j;
            if (j < 64 && nblk == 0) valid = false;
            if (j >= 128 && nblk == NB - 1) valid = false;
            const float sv = valid ? s[jt][r] * 0.125f : -1e30f;
            s[jt][r] = sv;
            m_ = fmaxf(m_, sv);
        }
#pragma unroll
        for (int st = 1; st < 16; st <<= 1)
            m_ = fmaxf(m_, __shfl_xor(m_, st, 64));
        float l_ = 0.f;
#pragma unroll
        for (int jt = 0; jt < 12; ++jt) {
            const float p = (s[jt][r] > -1e29f) ? __expf(s[jt][r] - m_) : 0.f;
            s[jt][r] = p;
            l_ += p;
        }
#pragma unroll
        for (int st = 1; st < 16; st <<= 1)
            l_ += __shfl_xor(l_, st, 64);
        const float inv = 1.f / l_;
#pragma unroll
        for (int jt = 0; jt < 12; ++jt) s[jt][r] *= inv;
    }

    __syncthreads();   // everyone done reading Ks before Ps overlays it

    // ---- late V write: regs -> Vt (swizzled); HBM latency hidden above ----
#pragma unroll
    for (int t = 0; t < 6; ++t) {
        const int e8 = (t * 256 + tid) * 8;
        const int kk = e8 >> 6, dd0 = e8 & 63;
        const int key = ((dd0 >> 3) & 7) << 4;
#pragma unroll
        for (int i = 0; i < 8; ++i) {
            const int boff = (dd0 + i) * (2 * VT_LD) + ((kk * 2) ^ key);
            *(bf16*)((char*)Vt + boff) = vv[t][i];
        }
    }

#pragma unroll
    for (int r = 0; r < 4; ++r) {
        const int prow = w * 16 + quad * 4 + r;
        const int rbase = prow * 384;
        const int key = (prow & 7) << 4;
#pragma unroll
        for (int jt = 0; jt < 12; ++jt) {
            const int boff = rbase + (((jt * 16 + lr) * 2) ^ key);
            *(bf16*)((char*)Ps + boff) = (bf16)s[jt][r];
        }
    }
    __syncthreads();   // covers both Vt and Ps writes

    // ---- phase 2: O = P V  (B-operand = V^T rows = dd) ----
    f32x4 o[4] = {};
    const int prow = w * 16 + lr;
    const int pbase = prow * 384;
    const int pkey = (prow & 7) << 4;
    __builtin_amdgcn_s_setprio(1);
#pragma unroll
    for (int kt = 0; kt < 6; ++kt) {
        bf16x8 ap = *(const bf16x8*)((const char*)Ps + pbase + ((kt * 64 + quad * 16) ^ pkey));
#pragma unroll
        for (int nt = 0; nt < 4; ++nt) {
            const int dd = nt * 16 + lr;
            const int boff = dd * (2 * VT_LD) + ((kt * 64 + quad * 16) ^ (((dd >> 3) & 7) << 4));
            bf16x8 bv_ = *(const bf16x8*)((const char*)Vt + boff);
            o[nt] = MFMA16(ap, bv_, o[nt]);
        }
    }
    __builtin_amdgcn_s_setprio(0);
#pragma unroll
    for (int nt = 0; nt < 4; ++nt) {
        const int dd = nt * 16 + lr;
#pragma unroll
        for (int r = 0; r < 4; ++r) {
            const int i = w * 16 + quad * 4 + r;
            ob[(size_t)(grow + i) * C_DIM + colbase + dd] = (bf16)o[nt][r];
        }
    }
}

// ---------------------------------------------------------------------------
// Kernel 3: output projection, 256x256 8-phase, f32 out. 1D grid 256,
// XCD-swizzled: work = (bid&7)*32 + bid>>3 -> XCD x owns 8 whole A-panels.
// ---------------------------------------------------------------------------
__global__ __launch_bounds__(512) void outproj256_kernel(
    const bf16* __restrict__ o, const bf16* __restrict__ Wob,
    const void* __restrict__ bo, float* __restrict__ out,
    const int* __restrict__ flag)
{
    __shared__ __align__(16) bf16 sm[65536];

    const int isf = *flag;
    const int bid = blockIdx.x;
    const int work = (bid & 7) * 32 + (bid >> 3);   // bijective, 256 % 8 == 0
    const int n0 = (work & 3) * 256;
    const int m0 = (work >> 2) * 256;

    const int tid = threadIdx.x;
    const int w = tid >> 6, lane = tid & 63;
    const int wr = w >> 2, wc = w & 3;
    const int lr = lane & 15, quad = lane >> 4;

    f32x4 acc[8][4] = {};

    GEMM256_KLOOP(o, Wob)

    // epilogue: bias + f32 out via swizzled LDS bounce, two 128-row passes
    float bb[4];
#pragma unroll
    for (int ni = 0; ni < 4; ++ni)
        bb[ni] = rd1(bo, n0 + wc * 64 + ni * 16 + lr, isf);
#pragma unroll
    for (int hh = 0; hh < 2; ++hh) {
        __syncthreads();
        if (wr == hh) {
#pragma unroll
            for (int mi = 0; mi < 8; ++mi)
#pragma unroll
                for (int ni = 0; ni < 4; ++ni)
#pragma unroll
                    for (int rr = 0; rr < 4; ++rr) {
                        const int lrow = mi * 16 + quad * 4 + rr;
                        const int col = wc * 64 + ni * 16 + lr;
                        *(float*)((char*)sm + lrow * 1024 + ((col * 4) ^ ((lrow & 7) << 4))) =
                            acc[mi][ni][rr] + bb[ni];
                    }
        }
        __syncthreads();
        // store: chunk-linear -> each wave writes one full row (1024B contiguous)
#pragma unroll
        for (int j = 0; j < 16; ++j) {
            const int idx = j * 512 + tid;
            const int row = idx >> 6, ch = idx & 63;
            u32x4 vls = *(const u32x4*)((const char*)sm + row * 1024 + ((ch * 16) ^ ((row & 7) << 4)));
            *(u32x4*)(out + (size_t)(m0 + hh * 128 + row) * C_DIM + n0 + ch * 4) = vls;
        }
    }
}

extern "C" void kernel_launch(void* const* d_in, const int* in_sizes, int n_in,
                              void* d_out, int out_size, void* d_ws, size_t ws_size,
                              hipStream_t stream) {
    const void* x  = d_in[0];
    const void* Wq = d_in[1];
    const void* bq = d_in[2];
    const void* Wk = d_in[3];
    const void* bk = d_in[4];
    const void* Wv = d_in[5];
    const void* bv = d_in[6];
    const void* Wo = d_in[7];
    const void* bo = d_in[8];
    float* out = (float*)d_out;

    const int sb = (out_size + 255) / 256;
    const bool sizes_ok = (n_in == 9) &&
        in_sizes[0] == (int)QKV_ELEMS &&
        in_sizes[1] == W_ELEMS && in_sizes[2] == C_DIM &&
        in_sizes[3] == W_ELEMS && in_sizes[4] == C_DIM &&
        in_sizes[5] == W_ELEMS && in_sizes[6] == C_DIM &&
        in_sizes[7] == W_ELEMS && in_sizes[8] == C_DIM &&
        out_size == (int)QKV_ELEMS;
    if (!sizes_ok) {
        sentinel_kernel<<<sb, 256, 0, stream>>>(out, 777.0f, out_size);
        return;
    }
    // ws: flag(4KB) | q(32MB) | k(32MB) | Wb(8MB)  = 72MB + 4KB
    const size_t need = 4096 + 2 * QKV_ELEMS * sizeof(bf16) + 4 * W_ELEMS * sizeof(bf16);
    if (ws_size < need) {
        sentinel_kernel<<<sb, 256, 0, stream>>>(out, 999.0f, out_size);
        return;
    }

    int* flag = (int*)d_ws;
    bf16* q  = (bf16*)((char*)d_ws + 4096);     // attn O in-place later
    bf16* k  = q + QKV_ELEMS;
    bf16* Wb = k + QKV_ELEMS;                   // Wq|Wk|Wv|Wo bf16
    // d_out (64MB f32) parking: xb in lower 32MB, v in upper 32MB; both dead
    // before outproj's f32 stores land (same-stream kernel ordering).
    bf16* xb = (bf16*)d_out;
    bf16* v  = (bf16*)((char*)d_out + QKV_ELEMS * sizeof(bf16));

    detect_kernel<<<1, 64, 0, stream>>>((const unsigned int*)x, flag);

    cvt_kernel<<<8192 + 4 * 512, 256, 0, stream>>>(x, xb, Wq, Wk, Wv, Wo, Wb, flag);

    qkv256_kernel<<<768, 512, 0, stream>>>(xb, Wb, bq, bk, bv, q, k, v, flag);

    attn_kernel<<<4096, 256, 0, stream>>>(q, k, v, q);

    outproj256_kernel<<<256, 512, 0, stream>>>(q, Wb + 3 * (size_t)W_ELEMS, bo, out, flag);
}